// Round 12
// baseline (1076.461 us; speedup 1.0000x reference)
//
#include <hip/hip_runtime.h>

// 2-layer hetero GraphSAGE, fp32 compute, bf16 gather tables, bucketed CSR build,
// persistent-weight register-tiled combines.
// HARD RULES (accumulated post-mortems):
//  R6/R7: one K-loop (one weight matrix tile) per kernel body — dual-weight
//    loops spill to 256 VGPR + scratch. Fusion via PRE operand, block-range
//    select, or CONCAT-K (stacked weights in ONE LDS tile, one loop).
//  R8: split gathers lower FETCH but not time (latency-bound) — keep fused dual gather.
//  R9 (VERIFIED 73.9-74.3us): gather = one coalesced offset-vector load + __shfl
//    distribution + 8-deep burst of row loads with per-lane masks + ZERO-INIT.
//    The zero-inits are LOAD-LIVENESS ANCHORS (force v0..v7 live together).
//  R10: removing the anchors serializes the burst (74.4 -> 79.6).
//  R11 (REVERTED): RUNTIME epilogue flags -> VGPR 248, occ 10%. Combine
//    polymorphism must be COMPILE-TIME. Block-range fusion of cold bodies ok.
//  R13 (VERIFIED −22us): concat-K layer-2 single pass; pre-gather hoist.
//  R14 (−5us only): hp/hu are L3-resident — sorted classifier kept (machinery
//    already paid for by the partition pass).
//  R15 (VERIFIED −10us): global histogram+scan DELETED; fixed-slack buckets.
//  R16 (481.2us BEST): partCast fusion; partition = 80us top dispatch
//    (occ 29% @49.7KB LDS, 1.24M LDS bank conflicts, WRITE 92MB).
//  R17/R18 (CRASH then 751us, REVERTED): per-edge returning-atomic scatter.
//    RULES: rank in LDS, one atomic per bucket per chunk; jointly-cleared
//    counters in ONE allocation (memset must cover the aligned span).
//  R19 (CRASHED, self-inflicted): u32 packing removed the key from staged
//    pairs; the bucket-recovery emitted was broken debris (8KB u16 map into a
//    2KB LDS slot). RULE: when packing removes a field, re-derive every
//    consumer; LDS sub-allocations need a byte-budget check.
//  R20: same design, correct recovery — bucket(j) = largest b with bx[b] <= j
//    (9-step binary search over the 512-entry LDS segment-start table; empty-
//    bucket ties resolve to the non-empty bucket). No extra LDS.

using u16 = unsigned short;
using u32 = unsigned int;

__device__ __forceinline__ u16 bf16r(float f) {            // round-to-nearest-even
    u32 b = __float_as_uint(f);
    b += 0x7fffu + ((b >> 16) & 1u);
    return (u16)(b >> 16);
}
__device__ __forceinline__ float2 bfup(u32 u) {            // (lo,hi) bf16 -> f32 pair
    return make_float2(__uint_as_float(u << 16), __uint_as_float(u & 0xffff0000u));
}

#define BSH 8          // bucket = key >> BSH, 256 node ids per bucket
#define MAXB 512       // max buckets per direction (NU=100000 -> 391)
#define CHUNK 4096     // edges per partition block
#define RPT 16         // CHUNK / 256

#define FMA_ROW(ACC, O, W4) \
    ACC[0] += (O) * (W4).x; ACC[1] += (O) * (W4).y; \
    ACC[2] += (O) * (W4).z; ACC[3] += (O) * (W4).w;

// ---- fused partition + cast + pre-gather ctile: 6 block ranges.
// [0,p) P edges; [p,2p) U edges; [2p,2p+l) label edges (payload = iota);
// [2p+l,ctStart) cast x_user -> bf16;
// [ctStart,ctStart+g128) ctile side0: bfB = bf16(xp@Wrl), fp32 -> sinkF (dead);
// [ctStart+g128,..) ctile side1: h_p = xp@Wbr, bf16 -> sinkB (dead).
// Pairs are u32: ((key&255)<<24) | payload  (bucket implicit in segment).
// LDS union: partition 26.0KB | ctile 33.3KB -> 33.3KB -> 4 blocks/CU.
__global__ __launch_bounds__(256) void k_partCast(
    const int* __restrict__ keysP, const int* __restrict__ payP,
    int* __restrict__ curPp, u32* __restrict__ pairsP, int NBP, int SLP,
    const int* __restrict__ keysU, const int* __restrict__ payU,
    int* __restrict__ curUp, u32* __restrict__ pairsU, int NBU, int SLU,
    int E, int pblocks,
    const int* __restrict__ keysL,
    int* __restrict__ curLp, u32* __restrict__ pairsL, int NBL, int SLL,
    int EL, int lblocks,
    const float* __restrict__ xc, u16* __restrict__ yc, int n8,
    int ctStart, int g128,
    const float* __restrict__ xp, const float* __restrict__ Wrl,
    const float* __restrict__ Wbr, u16* __restrict__ bfB,
    float* __restrict__ h_p, float* __restrict__ sinkF,
    u16* __restrict__ sinkB, int NPc) {
    __shared__ __align__(16) char smem[33280];
    int tid = threadIdx.x;
    int bix = blockIdx.x;
    if (bix >= ctStart) {                        // ---- ctile ranges (5,6) ----
        float* Ws = (float*)smem;                // 64*64 floats = 16384 B
        float* op = (float*)(smem + 16384);      // 32*132 floats = 16896 B
        int cbix = bix - ctStart;
        const float* W; float* h; u16* hbf;
        int bid;
        if (cbix < g128) { W = Wrl; h = sinkF; hbf = bfB;   bid = cbix; }
        else             { W = Wbr; h = h_p;   hbf = sinkB; bid = cbix - g128; }
        const int c4 = (tid & 15) * 4;
        const int rb = (tid >> 4) * 2;
        const int ntiles = (NPc + 31) / 32;
        for (int tile = bid; tile < ntiles; tile += g128) {
            const int row0 = tile * 32;
            __syncthreads();                     // prev tile's op reads done
            for (int i = tid; i < 32 * 32; i += 256) {
                int r = i >> 5, k4 = (i & 31) * 4;
                int row = row0 + r;
                float4 v = make_float4(0.f, 0.f, 0.f, 0.f);
                if (row < NPc) v = *(const float4*)(xp + (size_t)row * 128 + k4);
                *(float4*)(op + r * 132 + k4) = v;
            }
            float acc[2][4];
#pragma unroll
            for (int i = 0; i < 2; ++i) {
                acc[i][0] = 0.f; acc[i][1] = 0.f; acc[i][2] = 0.f; acc[i][3] = 0.f;
            }
            // K=128 in two 64-halves: Ws reloaded per half (weights L2-resident,
            // ~2 tiles/block -> trivial reload cost) to keep LDS at 33.3KB.
            for (int half = 0; half < 2; ++half) {
                __syncthreads();                 // prev half's Ws reads done
                for (int i = tid; i < 64 * 16; i += 256)
                    ((float4*)Ws)[i] = ((const float4*)(W + half * 64 * 64))[i];
                __syncthreads();                 // Ws (and op) visible
                const int kb = half * 64;
                for (int kk = 0; kk < 64; kk += 4) {
                    float4 w0 = *(const float4*)(Ws + (kk + 0) * 64 + c4);
                    float4 w1 = *(const float4*)(Ws + (kk + 1) * 64 + c4);
                    float4 w2 = *(const float4*)(Ws + (kk + 2) * 64 + c4);
                    float4 w3 = *(const float4*)(Ws + (kk + 3) * 64 + c4);
#pragma unroll
                    for (int i = 0; i < 2; ++i) {
                        float4 o = *(const float4*)(op + (rb + i) * 132 + kb + kk);
                        FMA_ROW(acc[i], o.x, w0);
                        FMA_ROW(acc[i], o.y, w1);
                        FMA_ROW(acc[i], o.z, w2);
                        FMA_ROW(acc[i], o.w, w3);
                    }
                }
            }
#pragma unroll
            for (int i = 0; i < 2; ++i) {
                int row = row0 + rb + i;
                if (row >= NPc) continue;
                float v0 = acc[i][0], v1 = acc[i][1], v2 = acc[i][2], v3 = acc[i][3];
                *(float4*)(h + (size_t)row * 64 + c4) = make_float4(v0, v1, v2, v3);
                uint2 o;
                o.x = (u32)bf16r(v0) | ((u32)bf16r(v1) << 16);
                o.y = (u32)bf16r(v2) | ((u32)bf16r(v3) << 16);
                *(uint2*)(hbf + (size_t)row * 64 + c4) = o;
            }
        }
        return;
    }
    if (bix >= 2 * pblocks + lblocks) {          // ---- cast range (4) ----
        int i = (bix - 2 * pblocks - lblocks) * 256 + tid;
        if (i < n8) {
            const float4* x4 = (const float4*)xc;
            float4 a = x4[i * 2], b = x4[i * 2 + 1];
            uint4 o;
            o.x = (u32)bf16r(a.x) | ((u32)bf16r(a.y) << 16);
            o.y = (u32)bf16r(a.z) | ((u32)bf16r(a.w) << 16);
            o.z = (u32)bf16r(b.x) | ((u32)bf16r(b.y) << 16);
            o.w = (u32)bf16r(b.z) | ((u32)bf16r(b.w) << 16);
            ((uint4*)yc)[i] = o;
        }
        return;
    }
    // ---- partition ranges (1-3) ----
    int* hist   = (int*)smem;                    // 512 ints  @ 0
    int* sA     = (int*)(smem + 2048);           // 512 ints
    int* sB     = (int*)(smem + 4096);           // 512 ints
    int* bx     = (int*)(smem + 6144);           // 512 ints (segment starts)
    int* gbase  = (int*)(smem + 8192);           // 512 ints
    u32* prs    = (u32*)(smem + 10240);          // 4096 u32 = 16384 B (ends 26624)
    const int* keys; const int* pay; int* cursor; u32* pairs;
    int NB, SL, cb, nE;
    if (bix < pblocks) {
        keys = keysP; pay = payP; cursor = curPp; pairs = pairsP; NB = NBP; SL = SLP;
        cb = bix; nE = E;
    } else if (bix < 2 * pblocks) {
        keys = keysU; pay = payU; cursor = curUp; pairs = pairsU; NB = NBU; SL = SLU;
        cb = bix - pblocks; nE = E;
    } else {
        keys = keysL; pay = nullptr; cursor = curLp; pairs = pairsL; NB = NBL; SL = SLL;
        cb = bix - 2 * pblocks; nE = EL;
    }
    int i0 = cb * CHUNK;
    int count = min(CHUNK, nE - i0);
    for (int i = tid; i < MAXB; i += 256) hist[i] = 0;
    __syncthreads();
    int keyr[RPT], payr[RPT], rankr[RPT];
#pragma unroll
    for (int r = 0; r < RPT; ++r) {
        int idx = r * 256 + tid;
        if (idx < count) {
            int k = keys[i0 + idx];
            keyr[r] = k;
            payr[r] = pay ? pay[i0 + idx] : (i0 + idx);
            rankr[r] = atomicAdd(&hist[k >> BSH], 1);
        } else keyr[r] = -1;
    }
    __syncthreads();
    // exclusive scan of per-chunk hist -> bx (ping-pong, 512 wide)
    sA[tid] = hist[tid]; sA[tid + 256] = hist[tid + 256];
    __syncthreads();
    int* src = sA; int* dst = sB;
    for (int off = 1; off < MAXB; off <<= 1) {
        dst[tid] = src[tid] + ((tid >= off) ? src[tid - off] : 0);
        int i2 = tid + 256;
        dst[i2] = src[i2] + ((i2 >= off) ? src[i2 - off] : 0);
        __syncthreads();
        int* t = src; src = dst; dst = t;
    }
    bx[tid] = src[tid] - hist[tid];
    bx[tid + 256] = src[tid + 256] - hist[tid + 256];
    __syncthreads();
    for (int b = tid; b < NB; b += 256) {
        int c = hist[b];
        gbase[b] = c ? (b * SL + atomicAdd(&cursor[b], c)) : 0;
    }
    // stage into LDS in bucket order (u32 packed)
#pragma unroll
    for (int r = 0; r < RPT; ++r) {
        if (keyr[r] >= 0)
            prs[bx[keyr[r] >> BSH] + rankr[r]] =
                ((u32)(keyr[r] & 255) << 24) | (u32)payr[r];
    }
    __syncthreads();
    // coalesced segment copy-out. Bucket of flat position j = largest b with
    // bx[b] <= j (bx non-decreasing; ties from empty buckets resolve to the
    // last — i.e. non-empty — bucket starting at j). 9-step binary search.
    for (int j = tid; j < count; j += 256) {
        int lo = 0, hi = NB - 1;
        while (lo < hi) {
            int mid = (lo + hi + 1) >> 1;
            if (bx[mid] <= j) lo = mid; else hi = mid - 1;
        }
        pairs[gbase[lo] + (j - bx[lo])] = prs[j];
    }
}

// ---- per-bucket fine fill -> nbr, deg, ptr(start); both directions fused ----
// Slack layout: bucket region = [bucket*SL, bucket*SL + cnt[bucket]).
// Pairs u32 packed: node-low8 = pr>>24, payload = pr & 0xFFFFFF.
// nbr stores BYTE offsets into the 128B-row bf16 tables (payload << 7).
__global__ __launch_bounds__(256) void k_bucketFill(
    const u32* __restrict__ pairsP, const int* __restrict__ cntP, int NBP, int SLP,
    int* __restrict__ nbr_p, int* __restrict__ deg_p, int* __restrict__ ptr_p, int NP,
    const u32* __restrict__ pairsU, const int* __restrict__ cntU, int NBU, int SLU,
    int* __restrict__ nbr_u, int* __restrict__ deg_u, int* __restrict__ ptr_u, int NU) {
    const u32* pairs; const int* cntA; int* nbr; int* deg; int* ptr;
    int N, SL, bucket;
    if ((int)blockIdx.x < NBP) {
        pairs = pairsP; cntA = cntP; nbr = nbr_p; deg = deg_p; ptr = ptr_p; N = NP;
        SL = SLP; bucket = blockIdx.x;
    } else {
        pairs = pairsU; cntA = cntU; nbr = nbr_u; deg = deg_u; ptr = ptr_u; N = NU;
        SL = SLU; bucket = blockIdx.x - NBP;
    }
    int tid = threadIdx.x;
    int base = bucket * SL;
    int cnt = cntA[bucket];
    __shared__ int h[256];
    __shared__ int s[256];
    __shared__ int cur[256];
    h[tid] = 0;
    __syncthreads();
    for (int j = tid; j < cnt; j += 256) atomicAdd(&h[pairs[base + j] >> 24], 1);
    __syncthreads();
    int d = h[tid];
    s[tid] = d;
    __syncthreads();
    for (int off = 1; off < 256; off <<= 1) {
        int v = (tid >= off) ? s[tid - off] : 0;
        __syncthreads();
        s[tid] += v;
        __syncthreads();
    }
    int excl = s[tid] - d;
    int node = bucket * 256 + tid;
    if (node < N) { deg[node] = d; ptr[node] = base + excl; }
    cur[tid] = excl;
    __syncthreads();
    for (int j = tid; j < cnt; j += 256) {
        u32 pr = pairs[base + j];
        int pos = atomicAdd(&cur[pr >> 24], 1);
        nbr[base + pos] = (int)((pr & 0xFFFFFFu) << 7);  // byte offset (128B rows)
    }
}

// R16: float2 accumulators — the two adds per dword fuse to v_pk_add_f32.
#define ACC8(A01,A23,A45,A67,V) \
    A01 += bfup((V).x); A23 += bfup((V).y); A45 += bfup((V).z); A67 += bfup((V).w);

// ------- fused dual gather-mean: nodes [0,NA) CSR A, [NA,NA+NB) CSR B -------
// wave per node; 8 lanes per bf16 row (uint4). R9 shape — do not restructure.
__global__ __launch_bounds__(256) void k_gather2(
    const u16* __restrict__ yA, const int* __restrict__ nbrA, const int* __restrict__ stpA,
    const int* __restrict__ degA, float* __restrict__ aggA, int NA,
    const u16* __restrict__ yB, const int* __restrict__ nbrB, const int* __restrict__ stpB,
    const int* __restrict__ degB, float* __restrict__ aggB, int NB) {
    int w = (blockIdx.x * 256 + threadIdx.x) >> 6;
    int lane = threadIdx.x & 63;
    if (w >= NA + NB) return;
    const u16* y; const int* nbr; const int* stp; const int* deg; float* agg; int n;
    if (w < NA) { y = yA; nbr = nbrA; stp = stpA; deg = degA; agg = aggA; n = w; }
    else        { y = yB; nbr = nbrB; stp = stpB; deg = degB; agg = aggB; n = w - NA; }
    const int q = lane >> 3, t = lane & 7;
    const int d = deg[n];
    const int st = stp[n];
    const char* yb = (const char*)y + t * 16;
    float2 a01 = make_float2(0.f, 0.f), a23 = make_float2(0.f, 0.f);
    float2 a45 = make_float2(0.f, 0.f), a67 = make_float2(0.f, 0.f);
    for (int j = 0; j < d; j += 64) {
        const int cnt = min(d - j, 64);           // wave-uniform
        int offv = 0;
        if (lane < cnt) offv = nbr[st + j + lane];   // one coalesced 256B load
        // distribute + burst-issue all row loads (independent, exec-masked tails)
#define GLD(R) \
        int g##R = __shfl(offv, R * 8 + q, 64); \
        uint4 v##R = make_uint4(0u, 0u, 0u, 0u); \
        if (R * 8 + q < cnt) v##R = *(const uint4*)(yb + g##R);
        GLD(0) GLD(1) GLD(2) GLD(3) GLD(4) GLD(5) GLD(6) GLD(7)
#undef GLD
        // accumulate (rounds beyond cnt are uniform-skipped; masked lanes hold 0)
#define ACCR(R) if (R * 8 < cnt) { ACC8(a01,a23,a45,a67,v##R) }
        ACCR(0) ACCR(1) ACCR(2) ACCR(3) ACCR(4) ACCR(5) ACCR(6) ACCR(7)
#undef ACCR
    }
#pragma unroll
    for (int m = 8; m < 64; m <<= 1) {
        a01.x += __shfl_xor(a01.x, m, 64); a01.y += __shfl_xor(a01.y, m, 64);
        a23.x += __shfl_xor(a23.x, m, 64); a23.y += __shfl_xor(a23.y, m, 64);
        a45.x += __shfl_xor(a45.x, m, 64); a45.y += __shfl_xor(a45.y, m, 64);
        a67.x += __shfl_xor(a67.x, m, 64); a67.y += __shfl_xor(a67.y, m, 64);
    }
    if (q == 0) {
        float dinv = 1.0f / (float)max(d, 1);
        float* dstp = agg + n * 64 + t * 8;
        *(float4*)dstp       = make_float4(a01.x * dinv, a01.y * dinv, a23.x * dinv, a23.y * dinv);
        *(float4*)(dstp + 4) = make_float4(a45.x * dinv, a45.y * dinv, a67.x * dinv, a67.y * dinv);
    }
}

// ======= paired combine: two independent K-dim problems, block-range selected =======
// COMPILE-TIME flags, IDENTICAL for both sides (R11 rule). Single K-loop body.
// h = act((PRE?pre:0) + (BIAS?b:0) + x@W); always STORE; optional RELU + EMIT.
template <int K, bool PRE, bool BIAS, bool RELU, bool EMIT>
__global__ __launch_bounds__(256) void k_ctilePairX(
    const float* __restrict__ pre0, const float* __restrict__ bias0,
    const float* __restrict__ x0, const float* __restrict__ W0,
    float* __restrict__ h0, u16* __restrict__ hbf0, int N0, int g0,
    const float* __restrict__ pre1, const float* __restrict__ bias1,
    const float* __restrict__ x1, const float* __restrict__ W1,
    float* __restrict__ h1, u16* __restrict__ hbf1, int N1) {
    constexpr int ROWS = (K == 64) ? 64 : 32;
    constexpr int RR = ROWS / 16;
    constexpr int STRIDE = K + 4;
    constexpr int KF4 = K / 4;
    __shared__ float Ws[K * 64];
    __shared__ float op[ROWS * STRIDE];
    const float* pre; const float* bias; const float* x; const float* W;
    float* h; u16* hbf;
    int N, bid, gsz;
    if ((int)blockIdx.x < g0) {
        pre = pre0; bias = bias0; x = x0; W = W0; h = h0; hbf = hbf0; N = N0;
        bid = blockIdx.x; gsz = g0;
    } else {
        pre = pre1; bias = bias1; x = x1; W = W1; h = h1; hbf = hbf1; N = N1;
        bid = blockIdx.x - g0; gsz = gridDim.x - g0;
    }
    const int tid = threadIdx.x;
    for (int i = tid; i < K * 16; i += 256)
        ((float4*)Ws)[i] = ((const float4*)W)[i];
    const int c4 = (tid & 15) * 4;
    const int rb = (tid >> 4) * RR;
    float bx_ = 0.f, by_ = 0.f, bz_ = 0.f, bw_ = 0.f;
    if (BIAS) {
        float4 b4 = *(const float4*)(bias + c4);
        bx_ = b4.x; by_ = b4.y; bz_ = b4.z; bw_ = b4.w;
    }
    const int ntiles = (N + ROWS - 1) / ROWS;
    for (int tile = bid; tile < ntiles; tile += gsz) {
        const int row0 = tile * ROWS;
        __syncthreads();
        for (int i = tid; i < ROWS * KF4; i += 256) {
            int r = i / KF4, k4 = (i % KF4) * 4;
            int row = row0 + r;
            float4 v = make_float4(0.f, 0.f, 0.f, 0.f);
            if (row < N) v = *(const float4*)(x + (size_t)row * K + k4);
            *(float4*)(op + r * STRIDE + k4) = v;
        }
        __syncthreads();
        float acc[RR][4];
#pragma unroll
        for (int i = 0; i < RR; ++i) {
            float px = 0.f, py = 0.f, pz = 0.f, pw = 0.f;
            if (PRE) {
                int row = row0 + rb + i;
                if (row < N) {
                    float4 p = *(const float4*)(pre + row * 64 + c4);
                    px = p.x; py = p.y; pz = p.z; pw = p.w;
                }
            }
            acc[i][0] = bx_ + px; acc[i][1] = by_ + py;
            acc[i][2] = bz_ + pz; acc[i][3] = bw_ + pw;
        }
        for (int kk = 0; kk < K; kk += 4) {
            float4 w0 = *(const float4*)(Ws + (kk + 0) * 64 + c4);
            float4 w1 = *(const float4*)(Ws + (kk + 1) * 64 + c4);
            float4 w2 = *(const float4*)(Ws + (kk + 2) * 64 + c4);
            float4 w3 = *(const float4*)(Ws + (kk + 3) * 64 + c4);
#pragma unroll
            for (int i = 0; i < RR; ++i) {
                float4 o = *(const float4*)(op + (rb + i) * STRIDE + kk);
                FMA_ROW(acc[i], o.x, w0);
                FMA_ROW(acc[i], o.y, w1);
                FMA_ROW(acc[i], o.z, w2);
                FMA_ROW(acc[i], o.w, w3);
            }
        }
#pragma unroll
        for (int i = 0; i < RR; ++i) {
            int row = row0 + rb + i;
            if (row >= N) continue;
            float v0 = acc[i][0], v1 = acc[i][1], v2 = acc[i][2], v3 = acc[i][3];
            if (RELU) {
                v0 = fmaxf(v0, 0.f); v1 = fmaxf(v1, 0.f);
                v2 = fmaxf(v2, 0.f); v3 = fmaxf(v3, 0.f);
            }
            *(float4*)(h + row * 64 + c4) = make_float4(v0, v1, v2, v3);
            if (EMIT) {
                uint2 o;
                o.x = (u32)bf16r(v0) | ((u32)bf16r(v1) << 16);
                o.y = (u32)bf16r(v2) | ((u32)bf16r(v3) << 16);
                *(uint2*)(hbf + row * 64 + c4) = o;
            }
        }
    }
}

// ======= paired CONCAT combine: h = bias + [xa|xb] @ [Wa;Wb], K=128 =======
// ONE K-loop, ONE LDS weight tile (filled from two 64x64 sources).
template <bool BIAS>
__global__ __launch_bounds__(256) void k_ctilePairCat(
    const float* __restrict__ bias0, const float* __restrict__ xa0,
    const float* __restrict__ xb0, const float* __restrict__ Wa0,
    const float* __restrict__ Wb0, float* __restrict__ h0, int N0, int g0,
    const float* __restrict__ bias1, const float* __restrict__ xa1,
    const float* __restrict__ xb1, const float* __restrict__ Wa1,
    const float* __restrict__ Wb1, float* __restrict__ h1, int N1) {
    constexpr int ROWS = 32, RR = 2, STRIDE = 132, KF4 = 32;
    __shared__ float Ws[128 * 64];
    __shared__ float op[ROWS * STRIDE];
    const float* bias; const float* xa; const float* xb;
    const float* Wa; const float* Wb; float* h;
    int N, bid, gsz;
    if ((int)blockIdx.x < g0) {
        bias = bias0; xa = xa0; xb = xb0; Wa = Wa0; Wb = Wb0; h = h0; N = N0;
        bid = blockIdx.x; gsz = g0;
    } else {
        bias = bias1; xa = xa1; xb = xb1; Wa = Wa1; Wb = Wb1; h = h1; N = N1;
        bid = blockIdx.x - g0; gsz = gridDim.x - g0;
    }
    const int tid = threadIdx.x;
    for (int i = tid; i < 64 * 16; i += 256) {
        ((float4*)Ws)[i]           = ((const float4*)Wa)[i];
        ((float4*)Ws)[64 * 16 + i] = ((const float4*)Wb)[i];
    }
    const int c4 = (tid & 15) * 4;
    const int rb = (tid >> 4) * RR;
    float bx_ = 0.f, by_ = 0.f, bz_ = 0.f, bw_ = 0.f;
    if (BIAS) {
        float4 b4 = *(const float4*)(bias + c4);
        bx_ = b4.x; by_ = b4.y; bz_ = b4.z; bw_ = b4.w;
    }
    const int ntiles = (N + ROWS - 1) / ROWS;
    for (int tile = bid; tile < ntiles; tile += gsz) {
        const int row0 = tile * ROWS;
        __syncthreads();
        for (int i = tid; i < ROWS * KF4; i += 256) {
            int r = i >> 5, k4 = (i & 31) * 4;
            int row = row0 + r;
            float4 v = make_float4(0.f, 0.f, 0.f, 0.f);
            if (row < N)
                v = (k4 < 64) ? *(const float4*)(xa + (size_t)row * 64 + k4)
                              : *(const float4*)(xb + (size_t)row * 64 + (k4 - 64));
            *(float4*)(op + r * STRIDE + k4) = v;
        }
        __syncthreads();
        float acc[RR][4];
#pragma unroll
        for (int i = 0; i < RR; ++i) {
            acc[i][0] = bx_; acc[i][1] = by_; acc[i][2] = bz_; acc[i][3] = bw_;
        }
        for (int kk = 0; kk < 128; kk += 4) {
            float4 w0 = *(const float4*)(Ws + (kk + 0) * 64 + c4);
            float4 w1 = *(const float4*)(Ws + (kk + 1) * 64 + c4);
            float4 w2 = *(const float4*)(Ws + (kk + 2) * 64 + c4);
            float4 w3 = *(const float4*)(Ws + (kk + 3) * 64 + c4);
#pragma unroll
            for (int i = 0; i < RR; ++i) {
                float4 o = *(const float4*)(op + (rb + i) * STRIDE + kk);
                FMA_ROW(acc[i], o.x, w0);
                FMA_ROW(acc[i], o.y, w1);
                FMA_ROW(acc[i], o.z, w2);
                FMA_ROW(acc[i], o.w, w3);
            }
        }
#pragma unroll
        for (int i = 0; i < RR; ++i) {
            int row = row0 + rb + i;
            if (row >= N) continue;
            *(float4*)(h + row * 64 + c4) =
                make_float4(acc[i][0], acc[i][1], acc[i][2], acc[i][3]);
        }
    }
}

// ------- sorted classifier over slack layout: slot -> (bucket=slot>>lsh,
// within=slot&(SLL-1)); valid iff within < cntL[bucket].
// Packed pairsL: p = (bucket<<8)|(pr>>24), e = pr & 0xFFFFFF. -------
__global__ __launch_bounds__(256) void k_classifyS(const float* __restrict__ hu,
                                                   const float* __restrict__ hp,
                                                   const int* __restrict__ lu,
                                                   const u32* __restrict__ pairsL,
                                                   const int* __restrict__ cntL,
                                                   int lsh,
                                                   float* __restrict__ out, int nslots) {
    int w = (blockIdx.x * 256 + threadIdx.x) >> 6;
    int lane = threadIdx.x & 63;
    int q = lane >> 4, t = lane & 15;
    int slot = w * 4 + q;
    float v = 0.f;
    int e = 0;
    bool ok = false;
    if (slot < nslots) {
        int bucket = slot >> lsh;
        int within = slot & ((1 << lsh) - 1);
        if (within < cntL[bucket]) {
            u32 pr = pairsL[slot];
            int p = (bucket << 8) | (int)(pr >> 24);
            e = (int)(pr & 0xFFFFFFu);
            int u = lu[e];
            float4 a = *(const float4*)(hu + (size_t)u * 64 + t * 4);
            float4 b = *(const float4*)(hp + (size_t)p * 64 + t * 4);
            v = a.x * b.x + a.y * b.y + a.z * b.z + a.w * b.w;
            ok = true;
        }
    }
#pragma unroll
    for (int m = 1; m < 16; m <<= 1) v += __shfl_xor(v, m, 64);
    if (t == 0 && ok) out[e] = v;
}

extern "C" void kernel_launch(void* const* d_in, const int* in_sizes, int n_in,
                              void* d_out, int out_size, void* d_ws, size_t ws_size,
                              hipStream_t stream) {
    const float* x_user    = (const float*)d_in[0];
    const float* x_product = (const float*)d_in[1];
    const float* W1bl = (const float*)d_in[2];
    const float* b1b  = (const float*)d_in[3];
    const float* W1br = (const float*)d_in[4];
    const float* W1rl = (const float*)d_in[5];
    const float* b1r  = (const float*)d_in[6];
    const float* W1rr = (const float*)d_in[7];
    const float* W2bl = (const float*)d_in[8];
    const float* b2b  = (const float*)d_in[9];
    const float* W2br = (const float*)d_in[10];
    const float* W2rl = (const float*)d_in[11];
    const float* b2r  = (const float*)d_in[12];
    const float* W2rr = (const float*)d_in[13];
    const int* esrc = (const int*)d_in[14];
    const int* edst = (const int*)d_in[15];
    const int* lu   = (const int*)d_in[16];
    const int* lp   = (const int*)d_in[17];

    const int NU = in_sizes[0] / 64;
    const int NP = in_sizes[1] / 128;
    const int E  = in_sizes[14];
    const int EL = in_sizes[16];
    const int NBP = (NP + 255) >> BSH;
    const int NBU = (NU + 255) >> BSH;
    const int NBL = NBP;                        // lab_p keys share the P id space

    // ---- slack sizes: mean + mean/8 + 1024 (>20 sigma for Binomial buckets) ----
    const int SLP = E / NBP + E / (NBP * 8) + 1024;
    const int SLU = E / NBU + E / (NBU * 8) + 1024;
    int lneed = EL / NBL + EL / (NBL * 4) + 512;
    int lsh = 1;
    while ((1 << lsh) < lneed) ++lsh;           // pow2 slack for labels (4096 here)
    const int SLL = 1 << lsh;

    // ---- workspace layout ----
    char* ws = (char*)d_ws;
    size_t off = 0;
    auto alloc = [&](size_t bytes) -> void* {
        void* p = ws + off;
        off += (bytes + 255) & ~(size_t)255;
        return p;
    };
    int*   deg_u  = (int*)alloc((size_t)NU * 4);
    int*   deg_p  = (int*)alloc((size_t)NP * 4);
    int*   ptr_u  = (int*)alloc((size_t)NU * 4);
    int*   ptr_p  = (int*)alloc((size_t)NP * 4);
    // R18 rule: jointly-cleared counters in ONE allocation.
    int*   curP   = (int*)alloc((size_t)MAXB * 3 * 4);
    int*   curU   = curP + MAXB;
    int*   curL   = curP + 2 * MAXB;
    int*   nbr_u  = (int*)alloc((size_t)NBU * SLU * 4);
    int*   nbr_p  = (int*)alloc((size_t)NBP * SLP * 4);
    u32*   pairsL = (u32*)alloc((size_t)NBL * SLL * 4);  // survives until classify
    // union region: pairs (CSR build) then agg (gather onward)
    size_t aggBytes = (size_t)(NP + NU) * 64 * 4;
    size_t pairBytes = ((size_t)NBP * SLP + (size_t)NBU * SLU) * 4;
    char* uni = (char*)alloc(aggBytes > pairBytes ? aggBytes : pairBytes);
    float* aggP   = (float*)uni;
    float* aggU   = (float*)(uni + (size_t)NP * 64 * 4);
    u32*   pairsP = (u32*)uni;
    u32*   pairsU = (u32*)(uni + (size_t)NBP * SLP * 4);
    u16*   bfA    = (u16*)alloc((size_t)NU * 64 * 2);  // x_user_bf, then h_u_bf
    u16*   bfB    = (u16*)alloc((size_t)NP * 64 * 2);  // y_p1_bf,  then h_p_bf
    float* h_p    = (float*)alloc((size_t)NP * 64 * 4);
    float* h_u    = (float*)alloc((size_t)NU * 64 * 4);
    // pre-gather dead-write sinks (h_u not yet live: fully overwritten later)
    float* sinkF  = h_u;                               // NP*64*4 = 12.8MB
    u16*   sinkB  = (u16*)((char*)h_u + (size_t)NP * 64 * 4);  // 6.4MB more

    const int tP32 = (NP + 31) / 32;
    const int tU32 = (NU + 31) / 32;
    const int tP64 = (NP + 63) / 64, tU64 = (NU + 63) / 64;
    auto cap = [](int t, int c) { return t < c ? t : c; };

    // ---- CSR build + label sort + cast + pre-gather ctile: ONE fused launch ----
    hipMemsetAsync(curP, 0, (size_t)MAXB * 3 * 4, stream);
    const int n8 = NU * 64 / 8;
    const int castBlocks = (n8 + 255) / 256;
    const int pblocks = (E + CHUNK - 1) / CHUNK;
    const int lblocks = (EL + CHUNK - 1) / CHUNK;
    const int g128 = cap(tP32, 768);
    const int ctStart = 2 * pblocks + lblocks + castBlocks;
    k_partCast<<<ctStart + 2 * g128, 256, 0, stream>>>(
        edst, esrc, curP, pairsP, NBP, SLP,
        esrc, edst, curU, pairsU, NBU, SLU, E, pblocks,
        lp, curL, pairsL, NBL, SLL, EL, lblocks,
        x_user, bfA, n8,
        ctStart, g128,
        x_product, W1rl, W1br, bfB, h_p, sinkF, sinkB, NP);
    k_bucketFill<<<NBP + NBU, 256, 0, stream>>>(
        pairsP, curP, NBP, SLP, nbr_p, deg_p, ptr_p, NP,
        pairsU, curU, NBU, SLU, nbr_u, deg_u, ptr_u, NU);

    // ---- layer 1: fused dual gather, then ONE paired combine ----
    k_gather2<<<(NP + NU + 3) / 4, 256, 0, stream>>>(bfA, nbr_p, ptr_p, deg_p, aggP, NP,
                                                     bfB, nbr_u, ptr_u, deg_u, aggU, NU);
    // side0: h_p = relu(h_p + b1b + aggP@W1bl), emit bfB
    // side1: h_u = relu(aggU + b1r + x_user@W1rr), emit bfA
    {
        const int gP = cap(tP64, 512), gU = cap(tU64, 1024);
        k_ctilePairX<64, true, true, true, true><<<gP + gU, 256, 0, stream>>>(
            h_p, b1b, aggP, W1bl, h_p, bfB, NP, gP,
            aggU, b1r, x_user, W1rr, h_u, bfA, NU);
    }

    // ---- layer 2: fused dual gather, then ONE concat-K combine ----
    k_gather2<<<(NP + NU + 3) / 4, 256, 0, stream>>>(bfA, nbr_p, ptr_p, deg_p, aggP, NP,
                                                     bfB, nbr_u, ptr_u, deg_u, aggU, NU);
    // side0: h_p = b2b + [aggP|h_p] @ [W2bl;W2br]
    // side1: h_u = b2r + [aggU|h_u] @ [W2rl;W2rr]
    {
        const int gP = cap(tP32, 512), gU = cap(tU32, 1024);
        k_ctilePairCat<true><<<gP + gU, 256, 0, stream>>>(
            b2b, aggP, h_p, W2bl, W2br, h_p, NP, gP,
            b2r, aggU, h_u, W2rl, W2rr, h_u, NU);
    }

    // ---- classifier over p-sorted label pairs (slack layout) ----
    const int nslots = NBL << lsh;
    k_classifyS<<<((nslots + 3) / 4 + 3) / 4, 256, 0, stream>>>(
        h_u, h_p, lu, pairsL, curL, lsh, (float*)d_out, nslots);
}

// Round 13
// 476.504 us; speedup vs baseline: 2.2591x; 2.2591x over previous
//
#include <hip/hip_runtime.h>

// 2-layer hetero GraphSAGE, fp32 compute, bf16 gather tables, bucketed CSR build,
// persistent-weight register-tiled combines.
// HARD RULES (accumulated post-mortems):
//  R6/R7: one K-loop (one weight matrix tile) per kernel body — dual-weight
//    loops spill to 256 VGPR + scratch. Fusion via PRE operand, block-range
//    select, or CONCAT-K (stacked weights in ONE LDS tile, one loop).
//  R8: split gathers lower FETCH but not time (latency-bound) — keep fused dual gather.
//  R9 (VERIFIED 73.9-74.3us): gather = one coalesced offset-vector load + __shfl
//    distribution + 8-deep burst of row loads with per-lane masks + ZERO-INIT.
//    The zero-inits are LOAD-LIVENESS ANCHORS (force v0..v7 live together).
//  R10: removing the anchors serializes the burst (74.4 -> 79.6).
//  R11 (REVERTED): RUNTIME epilogue flags -> VGPR 248, occ 10%. Combine
//    polymorphism must be COMPILE-TIME. Block-range fusion of cold bodies ok.
//  R13 (VERIFIED −22us): concat-K layer-2 single pass; pre-gather hoist.
//  R14 (−5us only): hp/hu are L3-resident.
//  R15 (VERIFIED −10us): global histogram+scan DELETED; fixed-slack buckets.
//  R16 (481.2us BEST — THIS KERNEL): float2/pk_add gather ACC; partCast fusion
//    (partition+label-sort+cast+pre-gather-ctile in one launch, 68 VGPR,
//    49.7KB LDS union).
//  R17-R20 (ALL REVERTED): build-restructuring arc failed 4x:
//    R17 direct-scatter (OOB crash: memset alignment gap) -> R18 fix = 751us
//    (returning global atomics: 292MB write-allocate, VALU 4%) -> R19 u32-pack
//    (crash: 8KB LDS map in 2KB slot) -> R20 pack+binary-search+2half-ctile =
//    1076us (VGPR 256, 1.5GB scratch spill traffic). RULES: rank in LDS, one
//    atomic per bucket per chunk; never per-element returning global atomics;
//    one change per round on a passing base; data-dependent loops inside the
//    hot partition body blow regalloc. The 80us build is a verified local
//    optimum — do not restructure it.

using u16 = unsigned short;
using u32 = unsigned int;

__device__ __forceinline__ u16 bf16r(float f) {            // round-to-nearest-even
    u32 b = __float_as_uint(f);
    b += 0x7fffu + ((b >> 16) & 1u);
    return (u16)(b >> 16);
}
__device__ __forceinline__ float2 bfup(u32 u) {            // (lo,hi) bf16 -> f32 pair
    return make_float2(__uint_as_float(u << 16), __uint_as_float(u & 0xffff0000u));
}

#define BSH 8          // bucket = key >> BSH, 256 node ids per bucket
#define MAXB 512       // max buckets per direction (NU=100000 -> 391)
#define CHUNK 4096     // edges per partition block
#define RPT 16         // CHUNK / 256

#define FMA_ROW(ACC, O, W4) \
    ACC[0] += (O) * (W4).x; ACC[1] += (O) * (W4).y; \
    ACC[2] += (O) * (W4).z; ACC[3] += (O) * (W4).w;

// ---- fused partition + cast + pre-gather ctile: 6 block ranges.
// [0,p) P edges; [p,2p) U edges; [2p,2p+l) label edges (payload = iota);
// [2p+l,ctStart) cast x_user -> bf16;
// [ctStart,ctStart+g128) ctile side0: bfB = bf16(xp@Wrl), fp32 -> sinkF (dead);
// [ctStart+g128,ctStart+2*g128) ctile side1: h_p = xp@Wbr, bf16 -> sinkB (dead).
// LDS explicitly unioned: partition 43.0KB | ctile 49.7KB -> 49.7KB.
__global__ __launch_bounds__(256) void k_partCast(
    const int* __restrict__ keysP, const int* __restrict__ payP,
    int* __restrict__ curPp, uint2* __restrict__ pairsP, int NBP, int SLP,
    const int* __restrict__ keysU, const int* __restrict__ payU,
    int* __restrict__ curUp, uint2* __restrict__ pairsU, int NBU, int SLU,
    int E, int pblocks,
    const int* __restrict__ keysL,
    int* __restrict__ curLp, uint2* __restrict__ pairsL, int NBL, int SLL,
    int EL, int lblocks,
    const float* __restrict__ xc, u16* __restrict__ yc, int n8,
    int ctStart, int g128,
    const float* __restrict__ xp, const float* __restrict__ Wrl,
    const float* __restrict__ Wbr, u16* __restrict__ bfB,
    float* __restrict__ h_p, float* __restrict__ sinkF,
    u16* __restrict__ sinkB, int NPc) {
    __shared__ __align__(16) char smem[49664];
    int tid = threadIdx.x;
    int bix = blockIdx.x;
    if (bix >= ctStart) {                        // ---- ctile ranges (5,6) ----
        float* Ws = (float*)smem;                // 128*64 floats = 32768 B
        float* op = (float*)(smem + 32768);      // 32*132 floats = 16896 B
        int cbix = bix - ctStart;
        const float* W; float* h; u16* hbf;
        int bid;
        if (cbix < g128) { W = Wrl; h = sinkF; hbf = bfB;   bid = cbix; }
        else             { W = Wbr; h = h_p;   hbf = sinkB; bid = cbix - g128; }
        for (int i = tid; i < 128 * 16; i += 256)
            ((float4*)Ws)[i] = ((const float4*)W)[i];
        const int c4 = (tid & 15) * 4;
        const int rb = (tid >> 4) * 2;
        const int ntiles = (NPc + 31) / 32;
        for (int tile = bid; tile < ntiles; tile += g128) {
            const int row0 = tile * 32;
            __syncthreads();
            for (int i = tid; i < 32 * 32; i += 256) {
                int r = i >> 5, k4 = (i & 31) * 4;
                int row = row0 + r;
                float4 v = make_float4(0.f, 0.f, 0.f, 0.f);
                if (row < NPc) v = *(const float4*)(xp + (size_t)row * 128 + k4);
                *(float4*)(op + r * 132 + k4) = v;
            }
            __syncthreads();
            float acc[2][4];
#pragma unroll
            for (int i = 0; i < 2; ++i) {
                acc[i][0] = 0.f; acc[i][1] = 0.f; acc[i][2] = 0.f; acc[i][3] = 0.f;
            }
            for (int kk = 0; kk < 128; kk += 4) {
                float4 w0 = *(const float4*)(Ws + (kk + 0) * 64 + c4);
                float4 w1 = *(const float4*)(Ws + (kk + 1) * 64 + c4);
                float4 w2 = *(const float4*)(Ws + (kk + 2) * 64 + c4);
                float4 w3 = *(const float4*)(Ws + (kk + 3) * 64 + c4);
#pragma unroll
                for (int i = 0; i < 2; ++i) {
                    float4 o = *(const float4*)(op + (rb + i) * 132 + kk);
                    FMA_ROW(acc[i], o.x, w0);
                    FMA_ROW(acc[i], o.y, w1);
                    FMA_ROW(acc[i], o.z, w2);
                    FMA_ROW(acc[i], o.w, w3);
                }
            }
#pragma unroll
            for (int i = 0; i < 2; ++i) {
                int row = row0 + rb + i;
                if (row >= NPc) continue;
                float v0 = acc[i][0], v1 = acc[i][1], v2 = acc[i][2], v3 = acc[i][3];
                *(float4*)(h + (size_t)row * 64 + c4) = make_float4(v0, v1, v2, v3);
                uint2 o;
                o.x = (u32)bf16r(v0) | ((u32)bf16r(v1) << 16);
                o.y = (u32)bf16r(v2) | ((u32)bf16r(v3) << 16);
                *(uint2*)(hbf + (size_t)row * 64 + c4) = o;
            }
        }
        return;
    }
    if (bix >= 2 * pblocks + lblocks) {          // ---- cast range (4) ----
        int i = (bix - 2 * pblocks - lblocks) * 256 + tid;
        if (i < n8) {
            const float4* x4 = (const float4*)xc;
            float4 a = x4[i * 2], b = x4[i * 2 + 1];
            uint4 o;
            o.x = (u32)bf16r(a.x) | ((u32)bf16r(a.y) << 16);
            o.y = (u32)bf16r(a.z) | ((u32)bf16r(a.w) << 16);
            o.z = (u32)bf16r(b.x) | ((u32)bf16r(b.y) << 16);
            o.w = (u32)bf16r(b.z) | ((u32)bf16r(b.w) << 16);
            ((uint4*)yc)[i] = o;
        }
        return;
    }
    // ---- partition ranges (1-3) ----
    int* hist   = (int*)smem;                    // 512 ints
    int* sA     = (int*)(smem + 2048);
    int* sB     = (int*)(smem + 4096);
    int* bx     = (int*)(smem + 6144);
    int* gbase  = (int*)(smem + 8192);
    uint2* prs  = (uint2*)(smem + 10240);        // 4096 uint2 = 32768 B
    const int* keys; const int* pay; int* cursor; uint2* pairs;
    int NB, SL, cb, nE;
    if (bix < pblocks) {
        keys = keysP; pay = payP; cursor = curPp; pairs = pairsP; NB = NBP; SL = SLP;
        cb = bix; nE = E;
    } else if (bix < 2 * pblocks) {
        keys = keysU; pay = payU; cursor = curUp; pairs = pairsU; NB = NBU; SL = SLU;
        cb = bix - pblocks; nE = E;
    } else {
        keys = keysL; pay = nullptr; cursor = curLp; pairs = pairsL; NB = NBL; SL = SLL;
        cb = bix - 2 * pblocks; nE = EL;
    }
    int i0 = cb * CHUNK;
    int count = min(CHUNK, nE - i0);
    for (int i = tid; i < MAXB; i += 256) hist[i] = 0;
    __syncthreads();
    int keyr[RPT], payr[RPT], rankr[RPT];
#pragma unroll
    for (int r = 0; r < RPT; ++r) {
        int idx = r * 256 + tid;
        if (idx < count) {
            int k = keys[i0 + idx];
            keyr[r] = k;
            payr[r] = pay ? pay[i0 + idx] : (i0 + idx);
            rankr[r] = atomicAdd(&hist[k >> BSH], 1);
        } else keyr[r] = -1;
    }
    __syncthreads();
    // exclusive scan of per-chunk hist -> bx (ping-pong, 512 wide)
    sA[tid] = hist[tid]; sA[tid + 256] = hist[tid + 256];
    __syncthreads();
    int* src = sA; int* dst = sB;
    for (int off = 1; off < MAXB; off <<= 1) {
        dst[tid] = src[tid] + ((tid >= off) ? src[tid - off] : 0);
        int i2 = tid + 256;
        dst[i2] = src[i2] + ((i2 >= off) ? src[i2 - off] : 0);
        __syncthreads();
        int* t = src; src = dst; dst = t;
    }
    bx[tid] = src[tid] - hist[tid];
    bx[tid + 256] = src[tid + 256] - hist[tid + 256];
    __syncthreads();
    for (int b = tid; b < NB; b += 256) {
        int c = hist[b];
        gbase[b] = c ? (b * SL + atomicAdd(&cursor[b], c)) : 0;
    }
    // stage into LDS in bucket order
#pragma unroll
    for (int r = 0; r < RPT; ++r) {
        if (keyr[r] >= 0)
            prs[bx[keyr[r] >> BSH] + rankr[r]] = make_uint2((u32)keyr[r], (u32)payr[r]);
    }
    __syncthreads();
    // coalesced segment copy-out
    for (int j = tid; j < count; j += 256) {
        uint2 pr = prs[j];
        int b = pr.x >> BSH;
        pairs[gbase[b] + (j - bx[b])] = pr;
    }
}

// ---- per-bucket fine fill -> nbr, deg, ptr(start); both directions fused ----
// Slack layout: bucket region = [bucket*SL, bucket*SL + cnt[bucket]).
// nbr stores BYTE offsets into the 128B-row bf16 tables (id << 7).
__global__ __launch_bounds__(256) void k_bucketFill(
    const uint2* __restrict__ pairsP, const int* __restrict__ cntP, int NBP, int SLP,
    int* __restrict__ nbr_p, int* __restrict__ deg_p, int* __restrict__ ptr_p, int NP,
    const uint2* __restrict__ pairsU, const int* __restrict__ cntU, int NBU, int SLU,
    int* __restrict__ nbr_u, int* __restrict__ deg_u, int* __restrict__ ptr_u, int NU) {
    const uint2* pairs; const int* cntA; int* nbr; int* deg; int* ptr;
    int N, SL, bucket;
    if ((int)blockIdx.x < NBP) {
        pairs = pairsP; cntA = cntP; nbr = nbr_p; deg = deg_p; ptr = ptr_p; N = NP;
        SL = SLP; bucket = blockIdx.x;
    } else {
        pairs = pairsU; cntA = cntU; nbr = nbr_u; deg = deg_u; ptr = ptr_u; N = NU;
        SL = SLU; bucket = blockIdx.x - NBP;
    }
    int tid = threadIdx.x;
    int base = bucket * SL;
    int cnt = cntA[bucket];
    __shared__ int h[256];
    __shared__ int s[256];
    __shared__ int cur[256];
    h[tid] = 0;
    __syncthreads();
    for (int j = tid; j < cnt; j += 256) atomicAdd(&h[pairs[base + j].x & 255], 1);
    __syncthreads();
    int d = h[tid];
    s[tid] = d;
    __syncthreads();
    for (int off = 1; off < 256; off <<= 1) {
        int v = (tid >= off) ? s[tid - off] : 0;
        __syncthreads();
        s[tid] += v;
        __syncthreads();
    }
    int excl = s[tid] - d;
    int node = bucket * 256 + tid;
    if (node < N) { deg[node] = d; ptr[node] = base + excl; }
    cur[tid] = excl;
    __syncthreads();
    for (int j = tid; j < cnt; j += 256) {
        uint2 pr = pairs[base + j];
        int pos = atomicAdd(&cur[pr.x & 255], 1);
        nbr[base + pos] = (int)(pr.y << 7);     // byte offset of row (128B rows)
    }
}

// R16: float2 accumulators — the two adds per dword fuse to v_pk_add_f32.
#define ACC8(A01,A23,A45,A67,V) \
    A01 += bfup((V).x); A23 += bfup((V).y); A45 += bfup((V).z); A67 += bfup((V).w);

// ------- fused dual gather-mean: nodes [0,NA) CSR A, [NA,NA+NB) CSR B -------
// wave per node; 8 lanes per bf16 row (uint4). R9 shape — do not restructure.
__global__ __launch_bounds__(256) void k_gather2(
    const u16* __restrict__ yA, const int* __restrict__ nbrA, const int* __restrict__ stpA,
    const int* __restrict__ degA, float* __restrict__ aggA, int NA,
    const u16* __restrict__ yB, const int* __restrict__ nbrB, const int* __restrict__ stpB,
    const int* __restrict__ degB, float* __restrict__ aggB, int NB) {
    int w = (blockIdx.x * 256 + threadIdx.x) >> 6;
    int lane = threadIdx.x & 63;
    if (w >= NA + NB) return;
    const u16* y; const int* nbr; const int* stp; const int* deg; float* agg; int n;
    if (w < NA) { y = yA; nbr = nbrA; stp = stpA; deg = degA; agg = aggA; n = w; }
    else        { y = yB; nbr = nbrB; stp = stpB; deg = degB; agg = aggB; n = w - NA; }
    const int q = lane >> 3, t = lane & 7;
    const int d = deg[n];
    const int st = stp[n];
    const char* yb = (const char*)y + t * 16;
    float2 a01 = make_float2(0.f, 0.f), a23 = make_float2(0.f, 0.f);
    float2 a45 = make_float2(0.f, 0.f), a67 = make_float2(0.f, 0.f);
    for (int j = 0; j < d; j += 64) {
        const int cnt = min(d - j, 64);           // wave-uniform
        int offv = 0;
        if (lane < cnt) offv = nbr[st + j + lane];   // one coalesced 256B load
        // distribute + burst-issue all row loads (independent, exec-masked tails)
#define GLD(R) \
        int g##R = __shfl(offv, R * 8 + q, 64); \
        uint4 v##R = make_uint4(0u, 0u, 0u, 0u); \
        if (R * 8 + q < cnt) v##R = *(const uint4*)(yb + g##R);
        GLD(0) GLD(1) GLD(2) GLD(3) GLD(4) GLD(5) GLD(6) GLD(7)
#undef GLD
        // accumulate (rounds beyond cnt are uniform-skipped; masked lanes hold 0)
#define ACCR(R) if (R * 8 < cnt) { ACC8(a01,a23,a45,a67,v##R) }
        ACCR(0) ACCR(1) ACCR(2) ACCR(3) ACCR(4) ACCR(5) ACCR(6) ACCR(7)
#undef ACCR
    }
#pragma unroll
    for (int m = 8; m < 64; m <<= 1) {
        a01.x += __shfl_xor(a01.x, m, 64); a01.y += __shfl_xor(a01.y, m, 64);
        a23.x += __shfl_xor(a23.x, m, 64); a23.y += __shfl_xor(a23.y, m, 64);
        a45.x += __shfl_xor(a45.x, m, 64); a45.y += __shfl_xor(a45.y, m, 64);
        a67.x += __shfl_xor(a67.x, m, 64); a67.y += __shfl_xor(a67.y, m, 64);
    }
    if (q == 0) {
        float dinv = 1.0f / (float)max(d, 1);
        float* dstp = agg + n * 64 + t * 8;
        *(float4*)dstp       = make_float4(a01.x * dinv, a01.y * dinv, a23.x * dinv, a23.y * dinv);
        *(float4*)(dstp + 4) = make_float4(a45.x * dinv, a45.y * dinv, a67.x * dinv, a67.y * dinv);
    }
}

// ======= paired combine: two independent K-dim problems, block-range selected =======
// COMPILE-TIME flags, IDENTICAL for both sides (R11 rule). Single K-loop body.
// h = act((PRE?pre:0) + (BIAS?b:0) + x@W); always STORE; optional RELU + EMIT.
template <int K, bool PRE, bool BIAS, bool RELU, bool EMIT>
__global__ __launch_bounds__(256) void k_ctilePairX(
    const float* __restrict__ pre0, const float* __restrict__ bias0,
    const float* __restrict__ x0, const float* __restrict__ W0,
    float* __restrict__ h0, u16* __restrict__ hbf0, int N0, int g0,
    const float* __restrict__ pre1, const float* __restrict__ bias1,
    const float* __restrict__ x1, const float* __restrict__ W1,
    float* __restrict__ h1, u16* __restrict__ hbf1, int N1) {
    constexpr int ROWS = (K == 64) ? 64 : 32;
    constexpr int RR = ROWS / 16;
    constexpr int STRIDE = K + 4;
    constexpr int KF4 = K / 4;
    __shared__ float Ws[K * 64];
    __shared__ float op[ROWS * STRIDE];
    const float* pre; const float* bias; const float* x; const float* W;
    float* h; u16* hbf;
    int N, bid, gsz;
    if ((int)blockIdx.x < g0) {
        pre = pre0; bias = bias0; x = x0; W = W0; h = h0; hbf = hbf0; N = N0;
        bid = blockIdx.x; gsz = g0;
    } else {
        pre = pre1; bias = bias1; x = x1; W = W1; h = h1; hbf = hbf1; N = N1;
        bid = blockIdx.x - g0; gsz = gridDim.x - g0;
    }
    const int tid = threadIdx.x;
    for (int i = tid; i < K * 16; i += 256)
        ((float4*)Ws)[i] = ((const float4*)W)[i];
    const int c4 = (tid & 15) * 4;
    const int rb = (tid >> 4) * RR;
    float bx_ = 0.f, by_ = 0.f, bz_ = 0.f, bw_ = 0.f;
    if (BIAS) {
        float4 b4 = *(const float4*)(bias + c4);
        bx_ = b4.x; by_ = b4.y; bz_ = b4.z; bw_ = b4.w;
    }
    const int ntiles = (N + ROWS - 1) / ROWS;
    for (int tile = bid; tile < ntiles; tile += gsz) {
        const int row0 = tile * ROWS;
        __syncthreads();
        for (int i = tid; i < ROWS * KF4; i += 256) {
            int r = i / KF4, k4 = (i % KF4) * 4;
            int row = row0 + r;
            float4 v = make_float4(0.f, 0.f, 0.f, 0.f);
            if (row < N) v = *(const float4*)(x + (size_t)row * K + k4);
            *(float4*)(op + r * STRIDE + k4) = v;
        }
        __syncthreads();
        float acc[RR][4];
#pragma unroll
        for (int i = 0; i < RR; ++i) {
            float px = 0.f, py = 0.f, pz = 0.f, pw = 0.f;
            if (PRE) {
                int row = row0 + rb + i;
                if (row < N) {
                    float4 p = *(const float4*)(pre + row * 64 + c4);
                    px = p.x; py = p.y; pz = p.z; pw = p.w;
                }
            }
            acc[i][0] = bx_ + px; acc[i][1] = by_ + py;
            acc[i][2] = bz_ + pz; acc[i][3] = bw_ + pw;
        }
        for (int kk = 0; kk < K; kk += 4) {
            float4 w0 = *(const float4*)(Ws + (kk + 0) * 64 + c4);
            float4 w1 = *(const float4*)(Ws + (kk + 1) * 64 + c4);
            float4 w2 = *(const float4*)(Ws + (kk + 2) * 64 + c4);
            float4 w3 = *(const float4*)(Ws + (kk + 3) * 64 + c4);
#pragma unroll
            for (int i = 0; i < RR; ++i) {
                float4 o = *(const float4*)(op + (rb + i) * STRIDE + kk);
                FMA_ROW(acc[i], o.x, w0);
                FMA_ROW(acc[i], o.y, w1);
                FMA_ROW(acc[i], o.z, w2);
                FMA_ROW(acc[i], o.w, w3);
            }
        }
#pragma unroll
        for (int i = 0; i < RR; ++i) {
            int row = row0 + rb + i;
            if (row >= N) continue;
            float v0 = acc[i][0], v1 = acc[i][1], v2 = acc[i][2], v3 = acc[i][3];
            if (RELU) {
                v0 = fmaxf(v0, 0.f); v1 = fmaxf(v1, 0.f);
                v2 = fmaxf(v2, 0.f); v3 = fmaxf(v3, 0.f);
            }
            *(float4*)(h + row * 64 + c4) = make_float4(v0, v1, v2, v3);
            if (EMIT) {
                uint2 o;
                o.x = (u32)bf16r(v0) | ((u32)bf16r(v1) << 16);
                o.y = (u32)bf16r(v2) | ((u32)bf16r(v3) << 16);
                *(uint2*)(hbf + row * 64 + c4) = o;
            }
        }
    }
}

// ======= paired CONCAT combine: h = bias + [xa|xb] @ [Wa;Wb], K=128 =======
// ONE K-loop, ONE LDS weight tile (filled from two 64x64 sources).
template <bool BIAS>
__global__ __launch_bounds__(256) void k_ctilePairCat(
    const float* __restrict__ bias0, const float* __restrict__ xa0,
    const float* __restrict__ xb0, const float* __restrict__ Wa0,
    const float* __restrict__ Wb0, float* __restrict__ h0, int N0, int g0,
    const float* __restrict__ bias1, const float* __restrict__ xa1,
    const float* __restrict__ xb1, const float* __restrict__ Wa1,
    const float* __restrict__ Wb1, float* __restrict__ h1, int N1) {
    constexpr int ROWS = 32, RR = 2, STRIDE = 132, KF4 = 32;
    __shared__ float Ws[128 * 64];
    __shared__ float op[ROWS * STRIDE];
    const float* bias; const float* xa; const float* xb;
    const float* Wa; const float* Wb; float* h;
    int N, bid, gsz;
    if ((int)blockIdx.x < g0) {
        bias = bias0; xa = xa0; xb = xb0; Wa = Wa0; Wb = Wb0; h = h0; N = N0;
        bid = blockIdx.x; gsz = g0;
    } else {
        bias = bias1; xa = xa1; xb = xb1; Wa = Wa1; Wb = Wb1; h = h1; N = N1;
        bid = blockIdx.x - g0; gsz = gridDim.x - g0;
    }
    const int tid = threadIdx.x;
    for (int i = tid; i < 64 * 16; i += 256) {
        ((float4*)Ws)[i]           = ((const float4*)Wa)[i];
        ((float4*)Ws)[64 * 16 + i] = ((const float4*)Wb)[i];
    }
    const int c4 = (tid & 15) * 4;
    const int rb = (tid >> 4) * RR;
    float bx_ = 0.f, by_ = 0.f, bz_ = 0.f, bw_ = 0.f;
    if (BIAS) {
        float4 b4 = *(const float4*)(bias + c4);
        bx_ = b4.x; by_ = b4.y; bz_ = b4.z; bw_ = b4.w;
    }
    const int ntiles = (N + ROWS - 1) / ROWS;
    for (int tile = bid; tile < ntiles; tile += gsz) {
        const int row0 = tile * ROWS;
        __syncthreads();
        for (int i = tid; i < ROWS * KF4; i += 256) {
            int r = i >> 5, k4 = (i & 31) * 4;
            int row = row0 + r;
            float4 v = make_float4(0.f, 0.f, 0.f, 0.f);
            if (row < N)
                v = (k4 < 64) ? *(const float4*)(xa + (size_t)row * 64 + k4)
                              : *(const float4*)(xb + (size_t)row * 64 + (k4 - 64));
            *(float4*)(op + r * STRIDE + k4) = v;
        }
        __syncthreads();
        float acc[RR][4];
#pragma unroll
        for (int i = 0; i < RR; ++i) {
            acc[i][0] = bx_; acc[i][1] = by_; acc[i][2] = bz_; acc[i][3] = bw_;
        }
        for (int kk = 0; kk < 128; kk += 4) {
            float4 w0 = *(const float4*)(Ws + (kk + 0) * 64 + c4);
            float4 w1 = *(const float4*)(Ws + (kk + 1) * 64 + c4);
            float4 w2 = *(const float4*)(Ws + (kk + 2) * 64 + c4);
            float4 w3 = *(const float4*)(Ws + (kk + 3) * 64 + c4);
#pragma unroll
            for (int i = 0; i < RR; ++i) {
                float4 o = *(const float4*)(op + (rb + i) * STRIDE + kk);
                FMA_ROW(acc[i], o.x, w0);
                FMA_ROW(acc[i], o.y, w1);
                FMA_ROW(acc[i], o.z, w2);
                FMA_ROW(acc[i], o.w, w3);
            }
        }
#pragma unroll
        for (int i = 0; i < RR; ++i) {
            int row = row0 + rb + i;
            if (row >= N) continue;
            *(float4*)(h + row * 64 + c4) =
                make_float4(acc[i][0], acc[i][1], acc[i][2], acc[i][3]);
        }
    }
}

// ------- sorted classifier over slack layout: slot -> (bucket=slot>>lsh,
// within=slot&(SLL-1)); valid iff within < cntL[bucket]. pairsL = (p, e). -------
__global__ __launch_bounds__(256) void k_classifyS(const float* __restrict__ hu,
                                                   const float* __restrict__ hp,
                                                   const int* __restrict__ lu,
                                                   const uint2* __restrict__ pairsL,
                                                   const int* __restrict__ cntL,
                                                   int lsh,
                                                   float* __restrict__ out, int nslots) {
    int w = (blockIdx.x * 256 + threadIdx.x) >> 6;
    int lane = threadIdx.x & 63;
    int q = lane >> 4, t = lane & 15;
    int slot = w * 4 + q;
    float v = 0.f;
    int e = 0;
    bool ok = false;
    if (slot < nslots) {
        int bucket = slot >> lsh;
        int within = slot & ((1 << lsh) - 1);
        if (within < cntL[bucket]) {
            uint2 pr = pairsL[slot];
            int p = (int)pr.x;
            e = (int)pr.y;
            int u = lu[e];
            float4 a = *(const float4*)(hu + (size_t)u * 64 + t * 4);
            float4 b = *(const float4*)(hp + (size_t)p * 64 + t * 4);
            v = a.x * b.x + a.y * b.y + a.z * b.z + a.w * b.w;
            ok = true;
        }
    }
#pragma unroll
    for (int m = 1; m < 16; m <<= 1) v += __shfl_xor(v, m, 64);
    if (t == 0 && ok) out[e] = v;
}

extern "C" void kernel_launch(void* const* d_in, const int* in_sizes, int n_in,
                              void* d_out, int out_size, void* d_ws, size_t ws_size,
                              hipStream_t stream) {
    const float* x_user    = (const float*)d_in[0];
    const float* x_product = (const float*)d_in[1];
    const float* W1bl = (const float*)d_in[2];
    const float* b1b  = (const float*)d_in[3];
    const float* W1br = (const float*)d_in[4];
    const float* W1rl = (const float*)d_in[5];
    const float* b1r  = (const float*)d_in[6];
    const float* W1rr = (const float*)d_in[7];
    const float* W2bl = (const float*)d_in[8];
    const float* b2b  = (const float*)d_in[9];
    const float* W2br = (const float*)d_in[10];
    const float* W2rl = (const float*)d_in[11];
    const float* b2r  = (const float*)d_in[12];
    const float* W2rr = (const float*)d_in[13];
    const int* esrc = (const int*)d_in[14];
    const int* edst = (const int*)d_in[15];
    const int* lu   = (const int*)d_in[16];
    const int* lp   = (const int*)d_in[17];

    const int NU = in_sizes[0] / 64;
    const int NP = in_sizes[1] / 128;
    const int E  = in_sizes[14];
    const int EL = in_sizes[16];
    const int NBP = (NP + 255) >> BSH;
    const int NBU = (NU + 255) >> BSH;
    const int NBL = NBP;                        // lab_p keys share the P id space

    // ---- slack sizes: mean + mean/8 + 1024 (>20 sigma for Binomial buckets) ----
    const int SLP = E / NBP + E / (NBP * 8) + 1024;
    const int SLU = E / NBU + E / (NBU * 8) + 1024;
    int lneed = EL / NBL + EL / (NBL * 4) + 512;
    int lsh = 1;
    while ((1 << lsh) < lneed) ++lsh;           // pow2 slack for labels (4096 here)
    const int SLL = 1 << lsh;

    // ---- workspace layout ----
    char* ws = (char*)d_ws;
    size_t off = 0;
    auto alloc = [&](size_t bytes) -> void* {
        void* p = ws + off;
        off += (bytes + 255) & ~(size_t)255;
        return p;
    };
    int*   deg_u  = (int*)alloc((size_t)NU * 4);
    int*   deg_p  = (int*)alloc((size_t)NP * 4);
    int*   ptr_u  = (int*)alloc((size_t)NU * 4);
    int*   ptr_p  = (int*)alloc((size_t)NP * 4);
    // R18 rule: jointly-cleared counters in ONE allocation.
    int*   curP   = (int*)alloc((size_t)MAXB * 3 * 4);
    int*   curU   = curP + MAXB;
    int*   curL   = curP + 2 * MAXB;
    int*   nbr_u  = (int*)alloc((size_t)NBU * SLU * 4);
    int*   nbr_p  = (int*)alloc((size_t)NBP * SLP * 4);
    uint2* pairsL = (uint2*)alloc((size_t)NBL * SLL * 8);  // survives until classify
    // union region: pairs (CSR build) then agg (gather onward)
    size_t aggBytes = (size_t)(NP + NU) * 64 * 4;
    size_t pairBytes = ((size_t)NBP * SLP + (size_t)NBU * SLU) * 8;
    char* uni = (char*)alloc(aggBytes > pairBytes ? aggBytes : pairBytes);
    float* aggP   = (float*)uni;
    float* aggU   = (float*)(uni + (size_t)NP * 64 * 4);
    uint2* pairsP = (uint2*)uni;
    uint2* pairsU = (uint2*)(uni + (size_t)NBP * SLP * 8);
    u16*   bfA    = (u16*)alloc((size_t)NU * 64 * 2);  // x_user_bf, then h_u_bf
    u16*   bfB    = (u16*)alloc((size_t)NP * 64 * 2);  // y_p1_bf,  then h_p_bf
    float* h_p    = (float*)alloc((size_t)NP * 64 * 4);
    float* h_u    = (float*)alloc((size_t)NU * 64 * 4);
    // pre-gather dead-write sinks (h_u not yet live: fully overwritten later)
    float* sinkF  = h_u;                               // NP*64*4 = 12.8MB
    u16*   sinkB  = (u16*)((char*)h_u + (size_t)NP * 64 * 4);  // 6.4MB more

    const int tP32 = (NP + 31) / 32;
    const int tU32 = (NU + 31) / 32;
    const int tP64 = (NP + 63) / 64, tU64 = (NU + 63) / 64;
    auto cap = [](int t, int c) { return t < c ? t : c; };

    // ---- CSR build + label sort + cast + pre-gather ctile: ONE fused launch ----
    hipMemsetAsync(curP, 0, (size_t)MAXB * 3 * 4, stream);
    const int n8 = NU * 64 / 8;
    const int castBlocks = (n8 + 255) / 256;
    const int pblocks = (E + CHUNK - 1) / CHUNK;
    const int lblocks = (EL + CHUNK - 1) / CHUNK;
    const int g128 = cap(tP32, 768);
    const int ctStart = 2 * pblocks + lblocks + castBlocks;
    k_partCast<<<ctStart + 2 * g128, 256, 0, stream>>>(
        edst, esrc, curP, pairsP, NBP, SLP,
        esrc, edst, curU, pairsU, NBU, SLU, E, pblocks,
        lp, curL, pairsL, NBL, SLL, EL, lblocks,
        x_user, bfA, n8,
        ctStart, g128,
        x_product, W1rl, W1br, bfB, h_p, sinkF, sinkB, NP);
    k_bucketFill<<<NBP + NBU, 256, 0, stream>>>(
        pairsP, curP, NBP, SLP, nbr_p, deg_p, ptr_p, NP,
        pairsU, curU, NBU, SLU, nbr_u, deg_u, ptr_u, NU);

    // ---- layer 1: fused dual gather, then ONE paired combine ----
    k_gather2<<<(NP + NU + 3) / 4, 256, 0, stream>>>(bfA, nbr_p, ptr_p, deg_p, aggP, NP,
                                                     bfB, nbr_u, ptr_u, deg_u, aggU, NU);
    // side0: h_p = relu(h_p + b1b + aggP@W1bl), emit bfB
    // side1: h_u = relu(aggU + b1r + x_user@W1rr), emit bfA
    {
        const int gP = cap(tP64, 512), gU = cap(tU64, 1024);
        k_ctilePairX<64, true, true, true, true><<<gP + gU, 256, 0, stream>>>(
            h_p, b1b, aggP, W1bl, h_p, bfB, NP, gP,
            aggU, b1r, x_user, W1rr, h_u, bfA, NU);
    }

    // ---- layer 2: fused dual gather, then ONE concat-K combine ----
    k_gather2<<<(NP + NU + 3) / 4, 256, 0, stream>>>(bfA, nbr_p, ptr_p, deg_p, aggP, NP,
                                                     bfB, nbr_u, ptr_u, deg_u, aggU, NU);
    // side0: h_p = b2b + [aggP|h_p] @ [W2bl;W2br]
    // side1: h_u = b2r + [aggU|h_u] @ [W2rl;W2rr]
    {
        const int gP = cap(tP32, 512), gU = cap(tU32, 1024);
        k_ctilePairCat<true><<<gP + gU, 256, 0, stream>>>(
            b2b, aggP, h_p, W2bl, W2br, h_p, NP, gP,
            b2r, aggU, h_u, W2rl, W2rr, h_u, NU);
    }

    // ---- classifier over p-sorted label pairs (slack layout) ----
    const int nslots = NBL << lsh;
    k_classifyS<<<((nslots + 3) / 4 + 3) / 4, 256, 0, stream>>>(
        h_u, h_p, lu, pairsL, curL, lsh, (float*)d_out, nslots);
}